// Round 1
// baseline (3016.870 us; speedup 1.0000x reference)
//
#include <hip/hip_runtime.h>

#define HH 8
#define FIN 64
#define BKT 64        // dst nodes per bucket
#define BKT_SHIFT 6   // log2(BKT)

// ---------- helpers ----------
__device__ __forceinline__ float b2f(unsigned short u) {
  union { unsigned int i; float f; } x;
  x.i = ((unsigned int)u) << 16;
  return x.f;
}

__device__ __forceinline__ float lrelu(float x) { return x > 0.f ? x : 0.2f * x; }

// dtype-agnostic scalar load: isf=1 -> fp32 array, isf=0 -> bf16 array
__device__ __forceinline__ float ld(const void* p, int i, int isf) {
  return isf ? ((const float*)p)[i] : b2f(((const unsigned short*)p)[i]);
}

// ---------- dtype detection ----------
__global__ void detect_kernel(const unsigned short* __restrict__ x, int* __restrict__ flag) {
  __shared__ int s[256];
  int t = threadIdx.x;
  int cnt = 0;
  for (int i = t; i < 2048; i += 256) {
    int e = (x[i] >> 7) & 0xFF;
    if (e >= 0x90) cnt++;
  }
  s[t] = cnt;
  __syncthreads();
  for (int k = 128; k > 0; k >>= 1) {
    if (t < k) s[t] += s[t + k];
    __syncthreads();
  }
  if (t == 0) flag[0] = (s[0] >= 8) ? 1 : 0;
}

// ---------- fill ----------
__global__ void fill_u32(unsigned int* __restrict__ p, long long n, unsigned int v) {
  long long i = (long long)blockIdx.x * blockDim.x + threadIdx.x;
  if (i < n) p[i] = v;
}

// ---------- projection: h = x @ W + b, plus up to 3 attention dot-products ----------
__global__ void proj_kernel(const void* __restrict__ x,
                            const void* __restrict__ W,
                            const void* __restrict__ b,
                            float* __restrict__ h, int N,
                            const void* __restrict__ a0v, float* __restrict__ s0,
                            const void* __restrict__ a1v, float* __restrict__ s1,
                            const void* __restrict__ a2v, float* __restrict__ s2,
                            const int* __restrict__ flag) {
  __shared__ float Wl[FIN][HH];
  __shared__ float bl[HH];
  __shared__ float al[3][HH];
  int isf = flag[0];
  int t = threadIdx.x;
  for (int i = t; i < FIN * HH; i += blockDim.x) Wl[i >> 3][i & 7] = ld(W, i, isf);
  if (t < HH) {
    bl[t] = ld(b, t, isf);
    al[0][t] = a0v ? ld(a0v, t, isf) : 0.f;
    al[1][t] = a1v ? ld(a1v, t, isf) : 0.f;
    al[2][t] = a2v ? ld(a2v, t, isf) : 0.f;
  }
  __syncthreads();
  int n = blockIdx.x * blockDim.x + t;
  if (n >= N) return;
  float acc[HH];
#pragma unroll
  for (int j = 0; j < HH; ++j) acc[j] = bl[j];
  if (isf) {
    const float4* xr = (const float4*)((const float*)x + (size_t)n * FIN);
#pragma unroll
    for (int v = 0; v < FIN / 4; ++v) {
      float4 p = xr[v];
      float f4[4] = {p.x, p.y, p.z, p.w};
#pragma unroll
      for (int k = 0; k < 4; ++k) {
        int f = v * 4 + k;
#pragma unroll
        for (int j = 0; j < HH; ++j) acc[j] += f4[k] * Wl[f][j];
      }
    }
  } else {
    const uint4* xr = (const uint4*)((const unsigned short*)x + (size_t)n * FIN);
#pragma unroll
    for (int v = 0; v < FIN / 8; ++v) {
      uint4 p = xr[v];
      unsigned int w[4] = {p.x, p.y, p.z, p.w};
#pragma unroll
      for (int k = 0; k < 4; ++k) {
        float f0 = __uint_as_float(w[k] << 16);
        float f1 = __uint_as_float(w[k] & 0xFFFF0000u);
        int f = v * 8 + k * 2;
#pragma unroll
        for (int j = 0; j < HH; ++j) acc[j] += f0 * Wl[f][j];
#pragma unroll
        for (int j = 0; j < HH; ++j) acc[j] += f1 * Wl[f + 1][j];
      }
    }
  }
  float* hn = h + (size_t)n * HH;
#pragma unroll
  for (int j = 0; j < HH; ++j) hn[j] = acc[j];
  float d0 = 0.f, d1 = 0.f, d2 = 0.f;
#pragma unroll
  for (int j = 0; j < HH; ++j) {
    d0 += acc[j] * al[0][j];
    d1 += acc[j] * al[1][j];
    d2 += acc[j] * al[2][j];
  }
  if (s0) s0[n] = d0;
  if (s1) s1[n] = d1;
  if (s2) s2[n] = d2;
}

// ---------- bucketed counting sort by dst, then LDS accumulation ----------
// Step 1: histogram of edges per BKT-node dst bucket.
__global__ void hist_kernel(const int* __restrict__ ei, int E, int* __restrict__ counts) {
  int e = blockIdx.x * blockDim.x + threadIdx.x;
  if (e >= E) return;
  int c = ei[E + e];
  atomicAdd(&counts[c >> BKT_SHIFT], 1);
}

// Step 2: exclusive scan of counts (single block of 256 threads).
// Writes offsets[] (segment start) and cursors[] (running allocator, init = start).
__global__ void scan_kernel(const int* __restrict__ counts, int nb,
                            int* __restrict__ offsets, int* __restrict__ cursors) {
  __shared__ int part[256];
  int t = threadIdx.x;
  int chunk = (nb + 255) / 256;
  int lo = t * chunk;
  int hi = lo + chunk; if (hi > nb) hi = nb;
  int s = 0;
  for (int i = lo; i < hi; ++i) s += counts[i];
  part[t] = s;
  __syncthreads();
  for (int d = 1; d < 256; d <<= 1) {
    int v = (t >= d) ? part[t - d] : 0;
    __syncthreads();
    part[t] += v;
    __syncthreads();
  }
  int base = (t == 0) ? 0 : part[t - 1];
  for (int i = lo; i < hi; ++i) {
    offsets[i] = base;
    cursors[i] = base;
    base += counts[i];
  }
}

// Step 3: scatter edges into bucket-sorted order with precomputed exp weight.
// Record: x = (local_c << 24) | r   (requires N < 2^24; N = 200K), y = bits(ex)
__global__ void scatter_kernel(const int* __restrict__ ei, int E,
                               const float* __restrict__ as, const float* __restrict__ ad,
                               int* __restrict__ cursors, uint2* __restrict__ sorted) {
  int e = blockIdx.x * blockDim.x + threadIdx.x;
  if (e >= E) return;
  int r = ei[e], c = ei[E + e];
  float a = lrelu(as[r] + ad[c]);
  float ex = __expf(a);
  int pos = atomicAdd(&cursors[c >> BKT_SHIFT], 1);
  uint2 v;
  v.x = ((unsigned)(c & (BKT - 1)) << 24) | (unsigned)r;
  v.y = __float_as_uint(ex);
  sorted[pos] = v;
}

// Step 4: one block per bucket; accumulate into LDS (ds_add_f32), write back
// with plain coalesced stores (bucket owns exclusive node range). No global
// float atomics anywhere.
__global__ void bucket_reduce(const uint2* __restrict__ sorted,
                              const int* __restrict__ offsets,
                              const int* __restrict__ cursors,
                              const float* __restrict__ h_src, int N,
                              float* __restrict__ den, float* __restrict__ out) {
  __shared__ float so[BKT][HH];
  __shared__ float sd[BKT];
  int b = blockIdx.x;
  int t = threadIdx.x;
  for (int i = t; i < BKT * HH; i += blockDim.x) so[i >> 3][i & 7] = 0.f;
  if (t < BKT) sd[t] = 0.f;
  __syncthreads();
  int start = offsets[b], end = cursors[b];
  for (int i = start + t; i < end; i += blockDim.x) {
    uint2 v = sorted[i];
    int lc = (int)(v.x >> 24);
    int r = (int)(v.x & 0xFFFFFFu);
    float ex = __uint_as_float(v.y);
    const float4* hp = (const float4*)(h_src + (size_t)r * HH);
    float4 h0 = hp[0];
    float4 h1 = hp[1];
    atomicAdd(&so[lc][0], ex * h0.x);
    atomicAdd(&so[lc][1], ex * h0.y);
    atomicAdd(&so[lc][2], ex * h0.z);
    atomicAdd(&so[lc][3], ex * h0.w);
    atomicAdd(&so[lc][4], ex * h1.x);
    atomicAdd(&so[lc][5], ex * h1.y);
    atomicAdd(&so[lc][6], ex * h1.z);
    atomicAdd(&so[lc][7], ex * h1.w);
    atomicAdd(&sd[lc], ex);
  }
  __syncthreads();
  int base = b * BKT;
  for (int i = t; i < BKT * HH; i += blockDim.x) {
    int n = base + (i >> 3);
    if (n < N) out[(size_t)n * HH + (i & 7)] = so[i >> 3][i & 7];
  }
  if (t < BKT) {
    int n = base + t;
    if (n < N) den[n] = sd[t];
  }
}

// ---------- semantic attention score: sum_n tanh(relu(o[n]/den) @ kW + kb) . q ----------
__global__ void score_kernel(const float* __restrict__ o0, const float* __restrict__ d0,
                             const float* __restrict__ o1, const float* __restrict__ d1,
                             int N,
                             const void* __restrict__ kW,
                             const void* __restrict__ kb,
                             const void* __restrict__ qv,
                             float* __restrict__ score,
                             const int* __restrict__ flag) {
  __shared__ float kWl[HH][HH];
  __shared__ float kbl[HH], ql[HH];
  __shared__ float red0[256], red1[256];
  int isf = flag[0];
  int t = threadIdx.x;
  if (t < HH * HH) kWl[t >> 3][t & 7] = ld(kW, t, isf);
  if (t < HH) { kbl[t] = ld(kb, t, isf); ql[t] = ld(qv, t, isf); }
  __syncthreads();
  int n = blockIdx.x * blockDim.x + t;
  float s0 = 0.f, s1 = 0.f;
  if (n < N) {
    const float* p0 = o0 + (size_t)n * HH;
    const float* p1 = o1 + (size_t)n * HH;
    float i0 = 1.f / (d0[n] + 1e-16f);
    float i1 = 1.f / (d1[n] + 1e-16f);
    float v0[HH], v1[HH];
#pragma unroll
    for (int j = 0; j < HH; ++j) { v0[j] = fmaxf(p0[j] * i0, 0.f); v1[j] = fmaxf(p1[j] * i1, 0.f); }
#pragma unroll
    for (int j = 0; j < HH; ++j) {
      float t0 = kbl[j], t1 = kbl[j];
#pragma unroll
      for (int i = 0; i < HH; ++i) { t0 += v0[i] * kWl[i][j]; t1 += v1[i] * kWl[i][j]; }
      s0 += tanhf(t0) * ql[j];
      s1 += tanhf(t1) * ql[j];
    }
  }
  red0[t] = s0; red1[t] = s1;
  __syncthreads();
  for (int s = 128; s > 0; s >>= 1) {
    if (t < s) { red0[t] += red0[t + s]; red1[t] += red1[t + s]; }
    __syncthreads();
  }
  if (t == 0) { atomicAdd(&score[0], red0[0]); atomicAdd(&score[1], red1[0]); }
}

// ---------- softmax over 2 metapaths + prediction head (fp32 output) ----------
__global__ void pred_kernel(const float* __restrict__ o0, const float* __restrict__ d0,
                            const float* __restrict__ o1, const float* __restrict__ d1,
                            int N,
                            const float* __restrict__ score,
                            const void* __restrict__ linW,
                            const void* __restrict__ linb,
                            float* __restrict__ outp,
                            const int* __restrict__ flag) {
  int isf = flag[0];
  int n = blockIdx.x * blockDim.x + threadIdx.x;
  if (n >= N) return;
  float s0 = score[0] / (float)N, s1 = score[1] / (float)N;
  float mx = fmaxf(s0, s1);
  float e0 = __expf(s0 - mx), e1 = __expf(s1 - mx);
  float inv = 1.f / (e0 + e1);
  float a0 = e0 * inv, a1 = e1 * inv;
  const float* p0 = o0 + (size_t)n * HH;
  const float* p1 = o1 + (size_t)n * HH;
  float i0 = 1.f / (d0[n] + 1e-16f);
  float i1 = 1.f / (d1[n] + 1e-16f);
  float acc = ld(linb, 0, isf);
#pragma unroll
  for (int j = 0; j < HH; ++j) {
    float z = a0 * fmaxf(p0[j] * i0, 0.f) + a1 * fmaxf(p1[j] * i1, 0.f);
    acc += z * ld(linW, j, isf);
  }
  outp[n] = 1.f / (1.f + __expf(-acc));
}

// ---------- launch ----------
extern "C" void kernel_launch(void* const* d_in, const int* in_sizes, int n_in,
                              void* d_out, int out_size, void* d_ws, size_t ws_size,
                              hipStream_t stream) {
  const int N = in_sizes[0] / FIN;

  const void* x_ind = d_in[0];
  const void* x_org = d_in[1];
  const void* x_ext = d_in[2];
  const int* ei_io = (const int*)d_in[3];  int E_io = in_sizes[3] / 2;  // ind->org
  const int* ei_oi = (const int*)d_in[4];  int E_oi = in_sizes[4] / 2;  // org->ind
  const int* ei_ei = (const int*)d_in[5];  int E_ei = in_sizes[5] / 2;  // ext->ind
  const int* ei_eo = (const int*)d_in[6];  int E_eo = in_sizes[6] / 2;  // ext->org
  const void* W_ind = d_in[7];
  const void* b_ind = d_in[8];
  const void* W_org = d_in[9];
  const void* b_org = d_in[10];
  const void* W_ext = d_in[11];
  const void* b_ext = d_in[12];
  const void* att_src_io = d_in[13];
  const void* att_dst_io = d_in[14];
  const void* att_src_oi = d_in[15];
  const void* att_dst_oi = d_in[16];
  const void* att_src_ei = d_in[17];
  const void* att_dst_ei = d_in[18];
  const void* att_src_eo = d_in[19];
  const void* att_dst_eo = d_in[20];
  const void* k_W = d_in[21];
  const void* k_b = d_in[22];
  const void* qv  = d_in[23];
  const void* lin_ind_W = d_in[24];
  const void* lin_ind_b = d_in[25];
  const void* lin_org_W = d_in[26];
  const void* lin_org_b = d_in[27];

  float* out_f = (float*)d_out;

  int E_max = E_io;
  if (E_oi > E_max) E_max = E_oi;
  if (E_ei > E_max) E_max = E_ei;
  if (E_eo > E_max) E_max = E_eo;

  const int nb = (N + BKT - 1) / BKT;  // dst buckets

  // workspace layout (floats)
  float* ws = (float*)d_ws;
  size_t off = 0;
  float* h_ind = ws + off; off += (size_t)N * HH;
  float* h_org = ws + off; off += (size_t)N * HH;
  float* h_ext = ws + off; off += (size_t)N * HH;
  float* as_io = ws + off; off += N;   // h_ind . att_src_ind_org
  float* ad_oi = ws + off; off += N;   // h_ind . att_dst_org_ind
  float* ad_ei = ws + off; off += N;   // h_ind . att_dst_ext_ind
  float* as_oi = ws + off; off += N;   // h_org . att_src_org_ind
  float* ad_io = ws + off; off += N;   // h_org . att_dst_ind_org
  float* ad_eo = ws + off; off += N;   // h_org . att_dst_ext_org
  float* as_ei = ws + off; off += N;   // h_ext . att_src_ext_ind
  float* as_eo = ws + off; off += N;   // h_ext . att_src_ext_org
  float* den_all = ws + off; off += (size_t)4 * N;       // per-mp denom (unnormalized)
  float* out_all = ws + off; off += (size_t)4 * N * HH;  // per-mp unnormalized sums [N,8]
  float* score_all = ws + off; off += 4;                 // 2 groups x 2 metapaths
  int* flag = (int*)(ws + off); off += 1;                // dtype flag
  int* counts  = (int*)(ws + off); off += nb;
  int* offsets = (int*)(ws + off); off += nb;
  int* cursors = (int*)(ws + off); off += nb;
  // align to 8B for uint2
  off = (off + 1) & ~(size_t)1;
  uint2* sorted = (uint2*)(ws + off); off += (size_t)2 * E_max;  // reused across metapaths

  const int BS = 256;
  const int nb_node = (N + BS - 1) / BS;

  detect_kernel<<<1, BS, 0, stream>>>((const unsigned short*)x_ind, flag);

  // zero score_all (den/out are fully written by bucket_reduce now)
  fill_u32<<<1, BS, 0, stream>>>((unsigned int*)score_all, 4, 0u);

  // projections + per-node attention scalars
  proj_kernel<<<nb_node, BS, 0, stream>>>(x_ind, W_ind, b_ind, h_ind, N,
                                          att_src_io, as_io, att_dst_oi, ad_oi, att_dst_ei, ad_ei, flag);
  proj_kernel<<<nb_node, BS, 0, stream>>>(x_org, W_org, b_org, h_org, N,
                                          att_src_oi, as_oi, att_dst_io, ad_io, att_dst_eo, ad_eo, flag);
  proj_kernel<<<nb_node, BS, 0, stream>>>(x_ext, W_ext, b_ext, h_ext, N,
                                          att_src_ei, as_ei, att_src_eo, as_eo,
                                          (const void*)nullptr, (float*)nullptr, flag);

  // metapath table: mp0 org->ind, mp1 ext->ind, mp2 ind->org, mp3 ext->org
  const int* eis[4]      = {ei_oi, ei_ei, ei_io, ei_eo};
  int        Es[4]       = {E_oi, E_ei, E_io, E_eo};
  const float* ass[4]    = {as_oi, as_ei, as_io, as_eo};
  const float* ads[4]    = {ad_oi, ad_ei, ad_io, ad_eo};
  const float* hsrcs[4]  = {h_org, h_ext, h_ind, h_ext};

  for (int mp = 0; mp < 4; ++mp) {
    int E = Es[mp];
    float* den = den_all + (size_t)mp * N;
    float* out = out_all + (size_t)mp * N * HH;
    int nbE = (E + BS - 1) / BS;
    fill_u32<<<(nb + BS - 1) / BS, BS, 0, stream>>>((unsigned int*)counts, nb, 0u);
    hist_kernel<<<nbE, BS, 0, stream>>>(eis[mp], E, counts);
    scan_kernel<<<1, BS, 0, stream>>>(counts, nb, offsets, cursors);
    scatter_kernel<<<nbE, BS, 0, stream>>>(eis[mp], E, ass[mp], ads[mp], cursors, sorted);
    bucket_reduce<<<nb, BS, 0, stream>>>(sorted, offsets, cursors, hsrcs[mp], N, den, out);
  }

  // semantic attention per group: ind = (mp0, mp1), org = (mp2, mp3)
  float* o_ind0 = out_all + (size_t)0 * N * HH;
  float* o_ind1 = out_all + (size_t)1 * N * HH;
  float* o_org0 = out_all + (size_t)2 * N * HH;
  float* o_org1 = out_all + (size_t)3 * N * HH;
  float* d_ind0 = den_all + (size_t)0 * N;
  float* d_ind1 = den_all + (size_t)1 * N;
  float* d_org0 = den_all + (size_t)2 * N;
  float* d_org1 = den_all + (size_t)3 * N;

  score_kernel<<<nb_node, BS, 0, stream>>>(o_ind0, d_ind0, o_ind1, d_ind1, N,
                                           k_W, k_b, qv, score_all, flag);
  score_kernel<<<nb_node, BS, 0, stream>>>(o_org0, d_org0, o_org1, d_org1, N,
                                           k_W, k_b, qv, score_all + 2, flag);

  pred_kernel<<<nb_node, BS, 0, stream>>>(o_ind0, d_ind0, o_ind1, d_ind1, N, score_all,
                                          lin_ind_W, lin_ind_b, out_f, flag);
  pred_kernel<<<nb_node, BS, 0, stream>>>(o_org0, d_org0, o_org1, d_org1, N, score_all + 2,
                                          lin_org_W, lin_org_b, out_f + N, flag);
}

// Round 2
// 1311.359 us; speedup vs baseline: 2.3006x; 2.3006x over previous
//
#include <hip/hip_runtime.h>

#define HH 8
#define FIN 64
#define CHUNK 4096      // edges per partA block
#define NPB 1024        // dst nodes per coarse bucket
#define NPB_SHIFT 10
#define MAXNB 256       // max buckets (N <= 256K)

// ---------- helpers ----------
__device__ __forceinline__ float b2f(unsigned short u) {
  union { unsigned int i; float f; } x;
  x.i = ((unsigned int)u) << 16;
  return x.f;
}

__device__ __forceinline__ float lrelu(float x) { return x > 0.f ? x : 0.2f * x; }

// dtype-agnostic scalar load: isf=1 -> fp32 array, isf=0 -> bf16 array
__device__ __forceinline__ float ld(const void* p, int i, int isf) {
  return isf ? ((const float*)p)[i] : b2f(((const unsigned short*)p)[i]);
}

// ---------- dtype detection ----------
__global__ void detect_kernel(const unsigned short* __restrict__ x, int* __restrict__ flag) {
  __shared__ int s[256];
  int t = threadIdx.x;
  int cnt = 0;
  for (int i = t; i < 2048; i += 256) {
    int e = (x[i] >> 7) & 0xFF;
    if (e >= 0x90) cnt++;
  }
  s[t] = cnt;
  __syncthreads();
  for (int k = 128; k > 0; k >>= 1) {
    if (t < k) s[t] += s[t + k];
    __syncthreads();
  }
  if (t == 0) flag[0] = (s[0] >= 8) ? 1 : 0;
}

// ---------- fill ----------
__global__ void fill_u32(unsigned int* __restrict__ p, long long n, unsigned int v) {
  long long i = (long long)blockIdx.x * blockDim.x + threadIdx.x;
  if (i < n) p[i] = v;
}

// ---------- projection: h = x @ W + b, plus up to 3 attention dot-products ----------
__global__ void proj_kernel(const void* __restrict__ x,
                            const void* __restrict__ W,
                            const void* __restrict__ b,
                            float* __restrict__ h, int N,
                            const void* __restrict__ a0v, float* __restrict__ s0,
                            const void* __restrict__ a1v, float* __restrict__ s1,
                            const void* __restrict__ a2v, float* __restrict__ s2,
                            const int* __restrict__ flag) {
  __shared__ float Wl[FIN][HH];
  __shared__ float bl[HH];
  __shared__ float al[3][HH];
  int isf = flag[0];
  int t = threadIdx.x;
  for (int i = t; i < FIN * HH; i += blockDim.x) Wl[i >> 3][i & 7] = ld(W, i, isf);
  if (t < HH) {
    bl[t] = ld(b, t, isf);
    al[0][t] = a0v ? ld(a0v, t, isf) : 0.f;
    al[1][t] = a1v ? ld(a1v, t, isf) : 0.f;
    al[2][t] = a2v ? ld(a2v, t, isf) : 0.f;
  }
  __syncthreads();
  int n = blockIdx.x * blockDim.x + t;
  if (n >= N) return;
  float acc[HH];
#pragma unroll
  for (int j = 0; j < HH; ++j) acc[j] = bl[j];
  if (isf) {
    const float4* xr = (const float4*)((const float*)x + (size_t)n * FIN);
#pragma unroll
    for (int v = 0; v < FIN / 4; ++v) {
      float4 p = xr[v];
      float f4[4] = {p.x, p.y, p.z, p.w};
#pragma unroll
      for (int k = 0; k < 4; ++k) {
        int f = v * 4 + k;
#pragma unroll
        for (int j = 0; j < HH; ++j) acc[j] += f4[k] * Wl[f][j];
      }
    }
  } else {
    const uint4* xr = (const uint4*)((const unsigned short*)x + (size_t)n * FIN);
#pragma unroll
    for (int v = 0; v < FIN / 8; ++v) {
      uint4 p = xr[v];
      unsigned int w[4] = {p.x, p.y, p.z, p.w};
#pragma unroll
      for (int k = 0; k < 4; ++k) {
        float f0 = __uint_as_float(w[k] << 16);
        float f1 = __uint_as_float(w[k] & 0xFFFF0000u);
        int f = v * 8 + k * 2;
#pragma unroll
        for (int j = 0; j < HH; ++j) acc[j] += f0 * Wl[f][j];
#pragma unroll
        for (int j = 0; j < HH; ++j) acc[j] += f1 * Wl[f + 1][j];
      }
    }
  }
  float* hn = h + (size_t)n * HH;
#pragma unroll
  for (int j = 0; j < HH; ++j) hn[j] = acc[j];
  float d0 = 0.f, d1 = 0.f, d2 = 0.f;
#pragma unroll
  for (int j = 0; j < HH; ++j) {
    d0 += acc[j] * al[0][j];
    d1 += acc[j] * al[1][j];
    d2 += acc[j] * al[2][j];
  }
  if (s0) s0[n] = d0;
  if (s1) s1[n] = d1;
  if (s2) s2[n] = d2;
}

// ---------- partA: chunk-local bucket sort in LDS, coalesced flush ----------
// Each block owns edges [blockIdx.x*CHUNK, +CHUNK). Records grouped by coarse
// dst bucket (c >> NPB_SHIFT) inside LDS, then flushed contiguously to
// sorted[chunkStart ...]. Descriptor (globalOffset,count) per (bucket,chunk)
// stored transposed: desc[b * nchunks + k] so partB reads coalesced.
// Record: x = (local_c << 22) | r  (needs r < 2^22, local_c < 2^10), y = bits(exp)
__global__ void partA(const int* __restrict__ ei, int E, int NB, int nchunks,
                      const float* __restrict__ as, const float* __restrict__ ad,
                      uint2* __restrict__ sorted, int2* __restrict__ desc) {
  __shared__ uint2 buf[CHUNK];      // 32 KB
  __shared__ int cnt[MAXNB];
  __shared__ int cur[MAXNB];
  __shared__ int off[MAXNB];
  __shared__ int scn[MAXNB];
  int t = threadIdx.x;
  int k = blockIdx.x;
  int base = k * CHUNK;
  int len = E - base; if (len > CHUNK) len = CHUNK;
  cnt[t] = 0;
  __syncthreads();
  // pass 1: histogram of dst buckets
  for (int i = 0; i < CHUNK; i += 256) {
    if (i + t < len) {
      int c = ei[E + base + i + t];
      atomicAdd(&cnt[c >> NPB_SHIFT], 1);
    }
  }
  __syncthreads();
  // inclusive scan over 256 entries (Hillis-Steele)
  scn[t] = cnt[t];
  __syncthreads();
  for (int d = 1; d < 256; d <<= 1) {
    int v = (t >= d) ? scn[t - d] : 0;
    __syncthreads();
    scn[t] += v;
    __syncthreads();
  }
  int ex = (t == 0) ? 0 : scn[t - 1];
  off[t] = ex;
  cur[t] = ex;
  __syncthreads();
  // pass 2: compute record, place into LDS at bucket-sorted position
  for (int i = 0; i < CHUNK; i += 256) {
    if (i + t < len) {
      int e = base + i + t;
      int r = ei[e];
      int c = ei[E + e];
      float a = lrelu(as[r] + ad[c]);
      float exw = __expf(a);
      int b = c >> NPB_SHIFT;
      int p = atomicAdd(&cur[b], 1);
      uint2 v;
      v.x = ((unsigned)(c & (NPB - 1)) << 22) | (unsigned)r;
      v.y = __float_as_uint(exw);
      buf[p] = v;
    }
  }
  __syncthreads();
  // coalesced flush of the sorted chunk
  for (int j = t; j < len; j += 256) sorted[(size_t)base + j] = buf[j];
  // descriptors (transposed layout)
  if (t < NB) {
    int2 d;
    d.x = base + off[t];
    d.y = cnt[t];
    desc[(size_t)t * nchunks + k] = d;
  }
}

// ---------- partB: one block per bucket, LDS accumulation, plain stores ----------
// 1024 threads = 16 waves. Each lane owns one chunk-segment at a time and
// streams it; accumulate into acc[NPB][9] (out[0..7], den at 8) via ds_add.
__global__ void __launch_bounds__(1024)
partB(const uint2* __restrict__ sorted,
      const int2* __restrict__ desc, int nchunks, int NB,
      const float* __restrict__ h_src, int N,
      float* __restrict__ den, float* __restrict__ out) {
  __shared__ float acc[NPB * 9];    // 36 KB
  int b = blockIdx.x;
  int t = threadIdx.x;
  for (int i = t; i < NPB * 9; i += 1024) acc[i] = 0.f;
  __syncthreads();
  int wv = t >> 6, ln = t & 63;
  int per = (nchunks + 15) >> 4;          // chunks per wave
  int k0 = wv * per;
  int k1 = k0 + per; if (k1 > nchunks) k1 = nchunks;
  const int2* drow = desc + (size_t)b * nchunks;
  for (int kb = k0; kb < k1; kb += 64) {
    int k = kb + ln;
    int2 d = make_int2(0, 0);
    if (k < k1) d = drow[k];              // coalesced descriptor load
    int cn = d.y;
    int offp = d.x;
    for (int i = 0; i < cn; ++i) {
      uint2 v = sorted[(size_t)offp + i];
      int lc = (int)(v.x >> 22);
      int r = (int)(v.x & 0x3FFFFFu);
      float exw = __uint_as_float(v.y);
      const float4* hp = (const float4*)(h_src + (size_t)r * HH);
      float4 h0 = hp[0];
      float4 h1 = hp[1];
      float* a = &acc[lc * 9];
      atomicAdd(a + 0, exw * h0.x);
      atomicAdd(a + 1, exw * h0.y);
      atomicAdd(a + 2, exw * h0.z);
      atomicAdd(a + 3, exw * h0.w);
      atomicAdd(a + 4, exw * h1.x);
      atomicAdd(a + 5, exw * h1.y);
      atomicAdd(a + 6, exw * h1.z);
      atomicAdd(a + 7, exw * h1.w);
      atomicAdd(a + 8, exw);
    }
  }
  __syncthreads();
  int basen = b << NPB_SHIFT;
  for (int i = t; i < NPB * HH; i += 1024) {
    int n = basen + (i >> 3);
    if (n < N) out[(size_t)n * HH + (i & 7)] = acc[(i >> 3) * 9 + (i & 7)];
  }
  for (int i = t; i < NPB; i += 1024) {
    int n = basen + i;
    if (n < N) den[n] = acc[i * 9 + 8];
  }
}

// ---------- semantic attention score: sum_n tanh(relu(o[n]/den) @ kW + kb) . q ----------
__global__ void score_kernel(const float* __restrict__ o0, const float* __restrict__ d0,
                             const float* __restrict__ o1, const float* __restrict__ d1,
                             int N,
                             const void* __restrict__ kW,
                             const void* __restrict__ kb,
                             const void* __restrict__ qv,
                             float* __restrict__ score,
                             const int* __restrict__ flag) {
  __shared__ float kWl[HH][HH];
  __shared__ float kbl[HH], ql[HH];
  __shared__ float red0[256], red1[256];
  int isf = flag[0];
  int t = threadIdx.x;
  if (t < HH * HH) kWl[t >> 3][t & 7] = ld(kW, t, isf);
  if (t < HH) { kbl[t] = ld(kb, t, isf); ql[t] = ld(qv, t, isf); }
  __syncthreads();
  int n = blockIdx.x * blockDim.x + t;
  float s0 = 0.f, s1 = 0.f;
  if (n < N) {
    const float* p0 = o0 + (size_t)n * HH;
    const float* p1 = o1 + (size_t)n * HH;
    float i0 = 1.f / (d0[n] + 1e-16f);
    float i1 = 1.f / (d1[n] + 1e-16f);
    float v0[HH], v1[HH];
#pragma unroll
    for (int j = 0; j < HH; ++j) { v0[j] = fmaxf(p0[j] * i0, 0.f); v1[j] = fmaxf(p1[j] * i1, 0.f); }
#pragma unroll
    for (int j = 0; j < HH; ++j) {
      float t0 = kbl[j], t1 = kbl[j];
#pragma unroll
      for (int i = 0; i < HH; ++i) { t0 += v0[i] * kWl[i][j]; t1 += v1[i] * kWl[i][j]; }
      s0 += tanhf(t0) * ql[j];
      s1 += tanhf(t1) * ql[j];
    }
  }
  red0[t] = s0; red1[t] = s1;
  __syncthreads();
  for (int s = 128; s > 0; s >>= 1) {
    if (t < s) { red0[t] += red0[t + s]; red1[t] += red1[t + s]; }
    __syncthreads();
  }
  if (t == 0) { atomicAdd(&score[0], red0[0]); atomicAdd(&score[1], red1[0]); }
}

// ---------- softmax over 2 metapaths + prediction head (fp32 output) ----------
__global__ void pred_kernel(const float* __restrict__ o0, const float* __restrict__ d0,
                            const float* __restrict__ o1, const float* __restrict__ d1,
                            int N,
                            const float* __restrict__ score,
                            const void* __restrict__ linW,
                            const void* __restrict__ linb,
                            float* __restrict__ outp,
                            const int* __restrict__ flag) {
  int isf = flag[0];
  int n = blockIdx.x * blockDim.x + threadIdx.x;
  if (n >= N) return;
  float s0 = score[0] / (float)N, s1 = score[1] / (float)N;
  float mx = fmaxf(s0, s1);
  float e0 = __expf(s0 - mx), e1 = __expf(s1 - mx);
  float inv = 1.f / (e0 + e1);
  float a0 = e0 * inv, a1 = e1 * inv;
  const float* p0 = o0 + (size_t)n * HH;
  const float* p1 = o1 + (size_t)n * HH;
  float i0 = 1.f / (d0[n] + 1e-16f);
  float i1 = 1.f / (d1[n] + 1e-16f);
  float acc = ld(linb, 0, isf);
#pragma unroll
  for (int j = 0; j < HH; ++j) {
    float z = a0 * fmaxf(p0[j] * i0, 0.f) + a1 * fmaxf(p1[j] * i1, 0.f);
    acc += z * ld(linW, j, isf);
  }
  outp[n] = 1.f / (1.f + __expf(-acc));
}

// ---------- launch ----------
extern "C" void kernel_launch(void* const* d_in, const int* in_sizes, int n_in,
                              void* d_out, int out_size, void* d_ws, size_t ws_size,
                              hipStream_t stream) {
  const int N = in_sizes[0] / FIN;

  const void* x_ind = d_in[0];
  const void* x_org = d_in[1];
  const void* x_ext = d_in[2];
  const int* ei_io = (const int*)d_in[3];  int E_io = in_sizes[3] / 2;  // ind->org
  const int* ei_oi = (const int*)d_in[4];  int E_oi = in_sizes[4] / 2;  // org->ind
  const int* ei_ei = (const int*)d_in[5];  int E_ei = in_sizes[5] / 2;  // ext->ind
  const int* ei_eo = (const int*)d_in[6];  int E_eo = in_sizes[6] / 2;  // ext->org
  const void* W_ind = d_in[7];
  const void* b_ind = d_in[8];
  const void* W_org = d_in[9];
  const void* b_org = d_in[10];
  const void* W_ext = d_in[11];
  const void* b_ext = d_in[12];
  const void* att_src_io = d_in[13];
  const void* att_dst_io = d_in[14];
  const void* att_src_oi = d_in[15];
  const void* att_dst_oi = d_in[16];
  const void* att_src_ei = d_in[17];
  const void* att_dst_ei = d_in[18];
  const void* att_src_eo = d_in[19];
  const void* att_dst_eo = d_in[20];
  const void* k_W = d_in[21];
  const void* k_b = d_in[22];
  const void* qv  = d_in[23];
  const void* lin_ind_W = d_in[24];
  const void* lin_ind_b = d_in[25];
  const void* lin_org_W = d_in[26];
  const void* lin_org_b = d_in[27];

  float* out_f = (float*)d_out;

  int E_max = E_io;
  if (E_oi > E_max) E_max = E_oi;
  if (E_ei > E_max) E_max = E_ei;
  if (E_eo > E_max) E_max = E_eo;

  const int NBck = (N + NPB - 1) >> NPB_SHIFT;            // coarse dst buckets
  const int nchunks_max = (E_max + CHUNK - 1) / CHUNK;

  // workspace layout (floats)
  float* ws = (float*)d_ws;
  size_t off = 0;
  float* h_ind = ws + off; off += (size_t)N * HH;
  float* h_org = ws + off; off += (size_t)N * HH;
  float* h_ext = ws + off; off += (size_t)N * HH;
  float* as_io = ws + off; off += N;   // h_ind . att_src_ind_org
  float* ad_oi = ws + off; off += N;   // h_ind . att_dst_org_ind
  float* ad_ei = ws + off; off += N;   // h_ind . att_dst_ext_ind
  float* as_oi = ws + off; off += N;   // h_org . att_src_org_ind
  float* ad_io = ws + off; off += N;   // h_org . att_dst_ind_org
  float* ad_eo = ws + off; off += N;   // h_org . att_dst_ext_org
  float* as_ei = ws + off; off += N;   // h_ext . att_src_ext_ind
  float* as_eo = ws + off; off += N;   // h_ext . att_src_ext_org
  float* den_all = ws + off; off += (size_t)4 * N;       // per-mp denom (unnormalized)
  float* out_all = ws + off; off += (size_t)4 * N * HH;  // per-mp unnormalized sums [N,8]
  float* score_all = ws + off; off += 4;                 // 2 groups x 2 metapaths
  int* flag = (int*)(ws + off); off += 1;                // dtype flag
  // align to 8B
  off = (off + 1) & ~(size_t)1;
  int2* desc = (int2*)(ws + off); off += (size_t)2 * NBck * nchunks_max;
  uint2* sorted = (uint2*)(ws + off); off += (size_t)2 * E_max;  // reused across metapaths

  const int BS = 256;
  const int nb_node = (N + BS - 1) / BS;

  detect_kernel<<<1, BS, 0, stream>>>((const unsigned short*)x_ind, flag);

  // zero score_all (den/out are fully written by partB)
  fill_u32<<<1, BS, 0, stream>>>((unsigned int*)score_all, 4, 0u);

  // projections + per-node attention scalars
  proj_kernel<<<nb_node, BS, 0, stream>>>(x_ind, W_ind, b_ind, h_ind, N,
                                          att_src_io, as_io, att_dst_oi, ad_oi, att_dst_ei, ad_ei, flag);
  proj_kernel<<<nb_node, BS, 0, stream>>>(x_org, W_org, b_org, h_org, N,
                                          att_src_oi, as_oi, att_dst_io, ad_io, att_dst_eo, ad_eo, flag);
  proj_kernel<<<nb_node, BS, 0, stream>>>(x_ext, W_ext, b_ext, h_ext, N,
                                          att_src_ei, as_ei, att_src_eo, as_eo,
                                          (const void*)nullptr, (float*)nullptr, flag);

  // metapath table: mp0 org->ind, mp1 ext->ind, mp2 ind->org, mp3 ext->org
  const int* eis[4]      = {ei_oi, ei_ei, ei_io, ei_eo};
  int        Es[4]       = {E_oi, E_ei, E_io, E_eo};
  const float* ass[4]    = {as_oi, as_ei, as_io, as_eo};
  const float* ads[4]    = {ad_oi, ad_ei, ad_io, ad_eo};
  const float* hsrcs[4]  = {h_org, h_ext, h_ind, h_ext};

  for (int mp = 0; mp < 4; ++mp) {
    int E = Es[mp];
    float* den = den_all + (size_t)mp * N;
    float* out = out_all + (size_t)mp * N * HH;
    int nchunks = (E + CHUNK - 1) / CHUNK;
    partA<<<nchunks, BS, 0, stream>>>(eis[mp], E, NBck, nchunks, ass[mp], ads[mp], sorted, desc);
    partB<<<NBck, 1024, 0, stream>>>(sorted, desc, nchunks, NBck, hsrcs[mp], N, den, out);
  }

  // semantic attention per group: ind = (mp0, mp1), org = (mp2, mp3)
  float* o_ind0 = out_all + (size_t)0 * N * HH;
  float* o_ind1 = out_all + (size_t)1 * N * HH;
  float* o_org0 = out_all + (size_t)2 * N * HH;
  float* o_org1 = out_all + (size_t)3 * N * HH;
  float* d_ind0 = den_all + (size_t)0 * N;
  float* d_ind1 = den_all + (size_t)1 * N;
  float* d_org0 = den_all + (size_t)2 * N;
  float* d_org1 = den_all + (size_t)3 * N;

  score_kernel<<<nb_node, BS, 0, stream>>>(o_ind0, d_ind0, o_ind1, d_ind1, N,
                                           k_W, k_b, qv, score_all, flag);
  score_kernel<<<nb_node, BS, 0, stream>>>(o_org0, d_org0, o_org1, d_org1, N,
                                           k_W, k_b, qv, score_all + 2, flag);

  pred_kernel<<<nb_node, BS, 0, stream>>>(o_ind0, d_ind0, o_ind1, d_ind1, N, score_all,
                                          lin_ind_W, lin_ind_b, out_f, flag);
  pred_kernel<<<nb_node, BS, 0, stream>>>(o_org0, d_org0, o_org1, d_org1, N, score_all + 2,
                                          lin_org_W, lin_org_b, out_f + N, flag);
}

// Round 3
// 1153.541 us; speedup vs baseline: 2.6153x; 1.1368x over previous
//
#include <hip/hip_runtime.h>

#define HH 8
#define FIN 64
#define CHUNK 4096      // edges per partA block
#define NPB 512         // dst nodes per bucket (partB tile)
#define NPB_SHIFT 9
#define MAXNB 512       // max buckets: supports N <= 262144

// ---------- helpers ----------
__device__ __forceinline__ float b2f(unsigned short u) {
  union { unsigned int i; float f; } x;
  x.i = ((unsigned int)u) << 16;
  return x.f;
}

__device__ __forceinline__ float lrelu(float x) { return x > 0.f ? x : 0.2f * x; }

__device__ __forceinline__ float ld(const void* p, int i, int isf) {
  return isf ? ((const float*)p)[i] : b2f(((const unsigned short*)p)[i]);
}

// per-metapath argument bundle
struct MP {
  const int* ei;
  const float* as;
  const float* ad;
  const float* hs;
  float* den;
  float* out;
  uint2* sorted;
  int2* desc;      // chunk-major: desc[k * NB + bucket]
  int E;
  int nchunks;
};
struct MP4 { MP m[4]; };

// ---------- dtype detection ----------
__global__ void detect_kernel(const unsigned short* __restrict__ x, int* __restrict__ flag) {
  __shared__ int s[256];
  int t = threadIdx.x;
  int cnt = 0;
  for (int i = t; i < 2048; i += 256) {
    int e = (x[i] >> 7) & 0xFF;
    if (e >= 0x90) cnt++;
  }
  s[t] = cnt;
  __syncthreads();
  for (int k = 128; k > 0; k >>= 1) {
    if (t < k) s[t] += s[t + k];
    __syncthreads();
  }
  if (t == 0) flag[0] = (s[0] >= 8) ? 1 : 0;
}

// ---------- fill ----------
__global__ void fill_u32(unsigned int* __restrict__ p, long long n, unsigned int v) {
  long long i = (long long)blockIdx.x * blockDim.x + threadIdx.x;
  if (i < n) p[i] = v;
}

// ---------- projection: h = x @ W + b, plus up to 3 attention dot-products ----------
__global__ void proj_kernel(const void* __restrict__ x,
                            const void* __restrict__ W,
                            const void* __restrict__ b,
                            float* __restrict__ h, int N,
                            const void* __restrict__ a0v, float* __restrict__ s0,
                            const void* __restrict__ a1v, float* __restrict__ s1,
                            const void* __restrict__ a2v, float* __restrict__ s2,
                            const int* __restrict__ flag) {
  __shared__ float Wl[FIN][HH];
  __shared__ float bl[HH];
  __shared__ float al[3][HH];
  int isf = flag[0];
  int t = threadIdx.x;
  for (int i = t; i < FIN * HH; i += blockDim.x) Wl[i >> 3][i & 7] = ld(W, i, isf);
  if (t < HH) {
    bl[t] = ld(b, t, isf);
    al[0][t] = a0v ? ld(a0v, t, isf) : 0.f;
    al[1][t] = a1v ? ld(a1v, t, isf) : 0.f;
    al[2][t] = a2v ? ld(a2v, t, isf) : 0.f;
  }
  __syncthreads();
  int n = blockIdx.x * blockDim.x + t;
  if (n >= N) return;
  float acc[HH];
#pragma unroll
  for (int j = 0; j < HH; ++j) acc[j] = bl[j];
  if (isf) {
    const float4* xr = (const float4*)((const float*)x + (size_t)n * FIN);
#pragma unroll
    for (int v = 0; v < FIN / 4; ++v) {
      float4 p = xr[v];
      float f4[4] = {p.x, p.y, p.z, p.w};
#pragma unroll
      for (int k = 0; k < 4; ++k) {
        int f = v * 4 + k;
#pragma unroll
        for (int j = 0; j < HH; ++j) acc[j] += f4[k] * Wl[f][j];
      }
    }
  } else {
    const uint4* xr = (const uint4*)((const unsigned short*)x + (size_t)n * FIN);
#pragma unroll
    for (int v = 0; v < FIN / 8; ++v) {
      uint4 p = xr[v];
      unsigned int w[4] = {p.x, p.y, p.z, p.w};
#pragma unroll
      for (int k = 0; k < 4; ++k) {
        float f0 = __uint_as_float(w[k] << 16);
        float f1 = __uint_as_float(w[k] & 0xFFFF0000u);
        int f = v * 8 + k * 2;
#pragma unroll
        for (int j = 0; j < HH; ++j) acc[j] += f0 * Wl[f][j];
#pragma unroll
        for (int j = 0; j < HH; ++j) acc[j] += f1 * Wl[f + 1][j];
      }
    }
  }
  float* hn = h + (size_t)n * HH;
#pragma unroll
  for (int j = 0; j < HH; ++j) hn[j] = acc[j];
  float d0 = 0.f, d1 = 0.f, d2 = 0.f;
#pragma unroll
  for (int j = 0; j < HH; ++j) {
    d0 += acc[j] * al[0][j];
    d1 += acc[j] * al[1][j];
    d2 += acc[j] * al[2][j];
  }
  if (s0) s0[n] = d0;
  if (s1) s1[n] = d1;
  if (s2) s2[n] = d2;
}

// ---------- partA: chunked bucket sort with register-batched gathers ----------
// gridDim.y selects metapath. Key: x = (local_c << 22) | r  (r < 2^22).
__global__ void __launch_bounds__(256)
partA(MP4 a4, int mp_base, int NB) {
  const MP a = a4.m[mp_base + blockIdx.y];
  int k = blockIdx.x;
  if (k >= a.nchunks) return;
  __shared__ uint2 buf[CHUNK];      // 32 KB
  __shared__ int cnt[MAXNB];
  __shared__ int cur[MAXNB];
  __shared__ int off[MAXNB];
  __shared__ int part[256];
  int t = threadIdx.x;
  int E = a.E;
  int base = k * CHUNK;
  int len = E - base; if (len > CHUNK) len = CHUNK;
  for (int i = t; i < MAXNB; i += 256) cnt[i] = 0;
  __syncthreads();
  // pass 1: read r,c once; histogram; stash in registers (compile-time indexed)
  int rr[16], cc[16];
#pragma unroll
  for (int i = 0; i < 16; ++i) {
    int idx = i * 256 + t;
    rr[i] = -1;
    if (idx < len) {
      rr[i] = a.ei[base + idx];
      cc[i] = a.ei[E + base + idx];
      atomicAdd(&cnt[cc[i] >> NPB_SHIFT], 1);
    }
  }
  __syncthreads();
  // exclusive scan of cnt[0..NB)
  int per = (NB + 255) >> 8;
  int lo = t * per;
  int hi = lo + per; if (hi > NB) hi = NB;
  int s = 0;
  for (int i = lo; i < hi; ++i) s += cnt[i];
  part[t] = s;
  __syncthreads();
  for (int d = 1; d < 256; d <<= 1) {
    int v = (t >= d) ? part[t - d] : 0;
    __syncthreads();
    part[t] += v;
    __syncthreads();
  }
  int run = (t == 0) ? 0 : part[t - 1];
  for (int i = lo; i < hi; ++i) { off[i] = run; cur[i] = run; run += cnt[i]; }
  __syncthreads();
  // pass 2a: issue ALL gathers before any use (32 independent loads in flight)
  float asv[16], adv[16];
#pragma unroll
  for (int i = 0; i < 16; ++i) {
    if (rr[i] >= 0) { asv[i] = a.as[rr[i]]; adv[i] = a.ad[cc[i]]; }
  }
  // pass 2b: compute weight, place into LDS at bucket-sorted position
#pragma unroll
  for (int i = 0; i < 16; ++i) {
    if (rr[i] >= 0) {
      float ex = __expf(lrelu(asv[i] + adv[i]));
      int b = cc[i] >> NPB_SHIFT;
      int p = atomicAdd(&cur[b], 1);
      uint2 v;
      v.x = ((unsigned)(cc[i] & (NPB - 1)) << 22) | (unsigned)rr[i];
      v.y = __float_as_uint(ex);
      buf[p] = v;
    }
  }
  __syncthreads();
  // coalesced flush
  for (int j = t; j < len; j += 256) a.sorted[(size_t)base + j] = buf[j];
  // descriptors: chunk-major -> coalesced write here, broadcast read in partB
  for (int i = t; i < NB; i += 256) {
    int2 d;
    d.x = base + off[i];
    d.y = cnt[i];
    a.desc[(size_t)k * NB + i] = d;
  }
}

// ---------- partB: wave-cooperative accumulate (8 lanes per record) ----------
// Block = 512 thr (8 waves) per bucket; gridDim.y selects metapath.
// lane = 8*grp + feat; a wave handles 8 (then 16 via unroll) records at once:
// coalesced key reads, coalesced 32B h_src gathers, 1 LDS atomic per lane.
__global__ void __launch_bounds__(512)
partB(MP4 a4, int mp_base, int NB, int N) {
  const MP a = a4.m[mp_base + blockIdx.y];
  __shared__ float acc[NPB * 9];    // 18 KB; stride 9 (odd) spreads banks
  int b = blockIdx.x;
  int t = threadIdx.x;
  for (int i = t; i < NPB * 9; i += 512) acc[i] = 0.f;
  __syncthreads();
  int wv = t >> 6;       // 8 waves
  int ln = t & 63;
  int grp = ln >> 3;     // 8 record-slots per wave
  int feat = ln & 7;
  const uint2* keys = a.sorted;
  const float* hs = a.hs;
  const int2* dsc = a.desc;
  int nch = a.nchunks;
  for (int k = wv; k < nch; k += 8) {
    int2 d = dsc[(size_t)k * NB + b];   // wave-broadcast load
    int offp = d.x, cn = d.y;
    for (int i0 = 0; i0 < cn; i0 += 16) {
      int rec0 = i0 + grp;
      int rec1 = i0 + 8 + grp;
      bool v0 = rec0 < cn, v1 = rec1 < cn;
      uint2 k0 = v0 ? keys[(size_t)offp + rec0] : make_uint2(0u, 0u);
      uint2 k1 = v1 ? keys[(size_t)offp + rec1] : make_uint2(0u, 0u);
      float h0 = v0 ? hs[(size_t)(k0.x & 0x3FFFFFu) * HH + feat] : 0.f;
      float h1 = v1 ? hs[(size_t)(k1.x & 0x3FFFFFu) * HH + feat] : 0.f;
      if (v0) {
        float ex = __uint_as_float(k0.y);
        int lc = (int)(k0.x >> 22);
        atomicAdd(&acc[lc * 9 + feat], ex * h0);
        if (feat == 0) atomicAdd(&acc[lc * 9 + 8], ex);
      }
      if (v1) {
        float ex = __uint_as_float(k1.y);
        int lc = (int)(k1.x >> 22);
        atomicAdd(&acc[lc * 9 + feat], ex * h1);
        if (feat == 0) atomicAdd(&acc[lc * 9 + 8], ex);
      }
    }
  }
  __syncthreads();
  int basen = b << NPB_SHIFT;
  for (int i = t; i < NPB * HH; i += 512) {
    int n = basen + (i >> 3);
    if (n < N) a.out[(size_t)n * HH + (i & 7)] = acc[(i >> 3) * 9 + (i & 7)];
  }
  for (int i = t; i < NPB; i += 512) {
    int n = basen + i;
    if (n < N) a.den[n] = acc[i * 9 + 8];
  }
}

// ---------- semantic attention score ----------
__global__ void score_kernel(const float* __restrict__ o0, const float* __restrict__ d0,
                             const float* __restrict__ o1, const float* __restrict__ d1,
                             int N,
                             const void* __restrict__ kW,
                             const void* __restrict__ kb,
                             const void* __restrict__ qv,
                             float* __restrict__ score,
                             const int* __restrict__ flag) {
  __shared__ float kWl[HH][HH];
  __shared__ float kbl[HH], ql[HH];
  __shared__ float red0[256], red1[256];
  int isf = flag[0];
  int t = threadIdx.x;
  if (t < HH * HH) kWl[t >> 3][t & 7] = ld(kW, t, isf);
  if (t < HH) { kbl[t] = ld(kb, t, isf); ql[t] = ld(qv, t, isf); }
  __syncthreads();
  int n = blockIdx.x * blockDim.x + t;
  float s0 = 0.f, s1 = 0.f;
  if (n < N) {
    const float* p0 = o0 + (size_t)n * HH;
    const float* p1 = o1 + (size_t)n * HH;
    float i0 = 1.f / (d0[n] + 1e-16f);
    float i1 = 1.f / (d1[n] + 1e-16f);
    float v0[HH], v1[HH];
#pragma unroll
    for (int j = 0; j < HH; ++j) { v0[j] = fmaxf(p0[j] * i0, 0.f); v1[j] = fmaxf(p1[j] * i1, 0.f); }
#pragma unroll
    for (int j = 0; j < HH; ++j) {
      float t0 = kbl[j], t1 = kbl[j];
#pragma unroll
      for (int i = 0; i < HH; ++i) { t0 += v0[i] * kWl[i][j]; t1 += v1[i] * kWl[i][j]; }
      s0 += tanhf(t0) * ql[j];
      s1 += tanhf(t1) * ql[j];
    }
  }
  red0[t] = s0; red1[t] = s1;
  __syncthreads();
  for (int s = 128; s > 0; s >>= 1) {
    if (t < s) { red0[t] += red0[t + s]; red1[t] += red1[t + s]; }
    __syncthreads();
  }
  if (t == 0) { atomicAdd(&score[0], red0[0]); atomicAdd(&score[1], red1[0]); }
}

// ---------- softmax over 2 metapaths + prediction head ----------
__global__ void pred_kernel(const float* __restrict__ o0, const float* __restrict__ d0,
                            const float* __restrict__ o1, const float* __restrict__ d1,
                            int N,
                            const float* __restrict__ score,
                            const void* __restrict__ linW,
                            const void* __restrict__ linb,
                            float* __restrict__ outp,
                            const int* __restrict__ flag) {
  int isf = flag[0];
  int n = blockIdx.x * blockDim.x + threadIdx.x;
  if (n >= N) return;
  float s0 = score[0] / (float)N, s1 = score[1] / (float)N;
  float mx = fmaxf(s0, s1);
  float e0 = __expf(s0 - mx), e1 = __expf(s1 - mx);
  float inv = 1.f / (e0 + e1);
  float a0 = e0 * inv, a1 = e1 * inv;
  const float* p0 = o0 + (size_t)n * HH;
  const float* p1 = o1 + (size_t)n * HH;
  float i0 = 1.f / (d0[n] + 1e-16f);
  float i1 = 1.f / (d1[n] + 1e-16f);
  float acc = ld(linb, 0, isf);
#pragma unroll
  for (int j = 0; j < HH; ++j) {
    float z = a0 * fmaxf(p0[j] * i0, 0.f) + a1 * fmaxf(p1[j] * i1, 0.f);
    acc += z * ld(linW, j, isf);
  }
  outp[n] = 1.f / (1.f + __expf(-acc));
}

// ---------- launch ----------
extern "C" void kernel_launch(void* const* d_in, const int* in_sizes, int n_in,
                              void* d_out, int out_size, void* d_ws, size_t ws_size,
                              hipStream_t stream) {
  const int N = in_sizes[0] / FIN;

  const void* x_ind = d_in[0];
  const void* x_org = d_in[1];
  const void* x_ext = d_in[2];
  const int* ei_io = (const int*)d_in[3];  int E_io = in_sizes[3] / 2;  // ind->org
  const int* ei_oi = (const int*)d_in[4];  int E_oi = in_sizes[4] / 2;  // org->ind
  const int* ei_ei = (const int*)d_in[5];  int E_ei = in_sizes[5] / 2;  // ext->ind
  const int* ei_eo = (const int*)d_in[6];  int E_eo = in_sizes[6] / 2;  // ext->org
  const void* W_ind = d_in[7];
  const void* b_ind = d_in[8];
  const void* W_org = d_in[9];
  const void* b_org = d_in[10];
  const void* W_ext = d_in[11];
  const void* b_ext = d_in[12];
  const void* att_src_io = d_in[13];
  const void* att_dst_io = d_in[14];
  const void* att_src_oi = d_in[15];
  const void* att_dst_oi = d_in[16];
  const void* att_src_ei = d_in[17];
  const void* att_dst_ei = d_in[18];
  const void* att_src_eo = d_in[19];
  const void* att_dst_eo = d_in[20];
  const void* k_W = d_in[21];
  const void* k_b = d_in[22];
  const void* qv  = d_in[23];
  const void* lin_ind_W = d_in[24];
  const void* lin_ind_b = d_in[25];
  const void* lin_org_W = d_in[26];
  const void* lin_org_b = d_in[27];

  float* out_f = (float*)d_out;

  int E_max = E_io;
  if (E_oi > E_max) E_max = E_oi;
  if (E_ei > E_max) E_max = E_ei;
  if (E_eo > E_max) E_max = E_eo;

  const int NB = (N + NPB - 1) >> NPB_SHIFT;
  const int nchunks_max = (E_max + CHUNK - 1) / CHUNK;

  // workspace layout (floats)
  float* ws = (float*)d_ws;
  size_t off = 0;
  float* h_ind = ws + off; off += (size_t)N * HH;
  float* h_org = ws + off; off += (size_t)N * HH;
  float* h_ext = ws + off; off += (size_t)N * HH;
  float* as_io = ws + off; off += N;
  float* ad_oi = ws + off; off += N;
  float* ad_ei = ws + off; off += N;
  float* as_oi = ws + off; off += N;
  float* ad_io = ws + off; off += N;
  float* ad_eo = ws + off; off += N;
  float* as_ei = ws + off; off += N;
  float* as_eo = ws + off; off += N;
  float* den_all = ws + off; off += (size_t)4 * N;
  float* out_all = ws + off; off += (size_t)4 * N * HH;
  float* score_all = ws + off; off += 4;
  int* flag = (int*)(ws + off); off += 1;
  off = (off + 1) & ~(size_t)1;  // 8B align

  size_t desc_f = (size_t)2 * NB * nchunks_max;  // int2 per (chunk,bucket), in floats
  size_t sort_f = (size_t)2 * E_max;             // uint2 per edge, in floats
  // big mode: all 4 metapaths resident -> 2 fused launches
  bool big = (off + 4 * desc_f + 4 * sort_f) * sizeof(float) <= ws_size;
  int slots = big ? 4 : 1;
  int2* desc0 = (int2*)(ws + off); off += (size_t)slots * desc_f;
  uint2* sorted0 = (uint2*)(ws + off); off += (size_t)slots * sort_f;

  const int BS = 256;
  const int nb_node = (N + BS - 1) / BS;

  detect_kernel<<<1, BS, 0, stream>>>((const unsigned short*)x_ind, flag);
  fill_u32<<<1, BS, 0, stream>>>((unsigned int*)score_all, 4, 0u);

  proj_kernel<<<nb_node, BS, 0, stream>>>(x_ind, W_ind, b_ind, h_ind, N,
                                          att_src_io, as_io, att_dst_oi, ad_oi, att_dst_ei, ad_ei, flag);
  proj_kernel<<<nb_node, BS, 0, stream>>>(x_org, W_org, b_org, h_org, N,
                                          att_src_oi, as_oi, att_dst_io, ad_io, att_dst_eo, ad_eo, flag);
  proj_kernel<<<nb_node, BS, 0, stream>>>(x_ext, W_ext, b_ext, h_ext, N,
                                          att_src_ei, as_ei, att_src_eo, as_eo,
                                          (const void*)nullptr, (float*)nullptr, flag);

  // metapath table: mp0 org->ind, mp1 ext->ind, mp2 ind->org, mp3 ext->org
  const int* eis[4]      = {ei_oi, ei_ei, ei_io, ei_eo};
  int        Es[4]       = {E_oi, E_ei, E_io, E_eo};
  const float* ass[4]    = {as_oi, as_ei, as_io, as_eo};
  const float* ads[4]    = {ad_oi, ad_ei, ad_io, ad_eo};
  const float* hsrcs[4]  = {h_org, h_ext, h_ind, h_ext};

  MP4 a4;
  for (int mp = 0; mp < 4; ++mp) {
    MP& a = a4.m[mp];
    a.ei = eis[mp];
    a.as = ass[mp];
    a.ad = ads[mp];
    a.hs = hsrcs[mp];
    a.den = den_all + (size_t)mp * N;
    a.out = out_all + (size_t)mp * N * HH;
    a.sorted = (uint2*)((float*)sorted0 + (size_t)(big ? mp : 0) * sort_f);
    a.desc = (int2*)((float*)desc0 + (size_t)(big ? mp : 0) * desc_f);
    a.E = Es[mp];
    a.nchunks = (Es[mp] + CHUNK - 1) / CHUNK;
  }

  if (big) {
    partA<<<dim3(nchunks_max, 4), 256, 0, stream>>>(a4, 0, NB);
    partB<<<dim3(NB, 4), 512, 0, stream>>>(a4, 0, NB, N);
  } else {
    for (int mp = 0; mp < 4; ++mp) {
      partA<<<dim3(a4.m[mp].nchunks, 1), 256, 0, stream>>>(a4, mp, NB);
      partB<<<dim3(NB, 1), 512, 0, stream>>>(a4, mp, NB, N);
    }
  }

  float* o_ind0 = out_all + (size_t)0 * N * HH;
  float* o_ind1 = out_all + (size_t)1 * N * HH;
  float* o_org0 = out_all + (size_t)2 * N * HH;
  float* o_org1 = out_all + (size_t)3 * N * HH;
  float* d_ind0 = den_all + (size_t)0 * N;
  float* d_ind1 = den_all + (size_t)1 * N;
  float* d_org0 = den_all + (size_t)2 * N;
  float* d_org1 = den_all + (size_t)3 * N;

  score_kernel<<<nb_node, BS, 0, stream>>>(o_ind0, d_ind0, o_ind1, d_ind1, N,
                                           k_W, k_b, qv, score_all, flag);
  score_kernel<<<nb_node, BS, 0, stream>>>(o_org0, d_org0, o_org1, d_org1, N,
                                           k_W, k_b, qv, score_all + 2, flag);

  pred_kernel<<<nb_node, BS, 0, stream>>>(o_ind0, d_ind0, o_ind1, d_ind1, N, score_all,
                                          lin_ind_W, lin_ind_b, out_f, flag);
  pred_kernel<<<nb_node, BS, 0, stream>>>(o_org0, d_org0, o_org1, d_org1, N, score_all + 2,
                                          lin_org_W, lin_org_b, out_f + N, flag);
}